// Round 12
// baseline (576.205 us; speedup 1.0000x reference)
//
#include <hip/hip_runtime.h>

// ---------------------------------------------------------------------------
// ProteinGCNNet: 3x GCNConv + mean-pool + 2 FC layers.
// Round 12: v_dot2_f32_f16 GEMMs with k-pair-packed fp16 weights (halves the
// inner-loop instruction count, kills cvt, halves W bytes) + register
// double-buffered W prefetch (covers the L2 load latency that held VALUBusy
// at 47%). fp16 activations, LDS-staged fused pool, bucketed CSR kept.
// ---------------------------------------------------------------------------

typedef _Float16 f16;
typedef _Float16 f16x2 __attribute__((ext_vector_type(2)));
typedef _Float16 f16x4 __attribute__((ext_vector_type(4)));

static __host__ __device__ inline int cdiv(int a, int b) { return (a + b - 1) / b; }

constexpr int BSPAN = 512;
constexpr int EPB   = 4096;
constexpr int EPT   = EPB / 256;

template <int V>
__device__ __forceinline__ void vload(float* d, const float* s) {
    if constexpr (V == 1) { d[0] = s[0]; }
    else if constexpr (V == 2) { float2 t = *reinterpret_cast<const float2*>(s); d[0] = t.x; d[1] = t.y; }
    else if constexpr (V == 4) { float4 t = *reinterpret_cast<const float4*>(s); d[0] = t.x; d[1] = t.y; d[2] = t.z; d[3] = t.w; }
    else { vload<4>(d, s); vload<4>(d + 4, s + 4); }
}
// load V f16x2 pairs (V dwords)
template <int V>
__device__ __forceinline__ void vload_p(f16x2* d, const f16x2* s) {
    if constexpr (V == 2) { *reinterpret_cast<float2*>(d) = *reinterpret_cast<const float2*>(s); }
    else if constexpr (V == 4) { *reinterpret_cast<float4*>(d) = *reinterpret_cast<const float4*>(s); }
    else {
        *reinterpret_cast<float4*>(d)     = *reinterpret_cast<const float4*>(s);
        *reinterpret_cast<float4*>(d + 4) = *reinterpret_cast<const float4*>(s + 4);
    }
}

// ---- weight pack: W[K][F] fp32 -> Wp[(kp*F + j)*2 + p] = f16(W[2kp+p][j]) ---
__global__ void k_wpack(const float* __restrict__ W, f16* __restrict__ Wp, int K, int F) {
    int i = blockIdx.x * blockDim.x + threadIdx.x;
    if (i >= K * F) return;
    int kp = i / (2 * F);
    int r = i - kp * 2 * F;
    int j = r >> 1;
    int p = r & 1;
    Wp[i] = (f16)W[(2 * kp + p) * F + j];
}

// ---- zero psum (float) + bktCnt (int) --------------------------------------
__global__ void k_zero2(float* pf, int nf, int* pi, int ni) {
    int i = blockIdx.x * blockDim.x + threadIdx.x;
    if (i < nf) pf[i] = 0.f;
    if (i < ni) pi[i] = 0;
}

// ---- A1: per-block LDS bucket histogram ------------------------------------
__global__ __launch_bounds__(256) void k_bkt_hist(const int* __restrict__ col,
                                                  int* bktCnt, int e, int nb) {
    __shared__ int hist[256];
    int t = threadIdx.x;
    hist[t] = 0;
    __syncthreads();
    int base = blockIdx.x * EPB;
#pragma unroll
    for (int j = 0; j < EPT; j++) {
        int idx = base + j * 256 + t;
        if (idx < e) atomicAdd(&hist[col[idx] >> 9], 1);
    }
    __syncthreads();
    if (t < nb && hist[t] > 0) atomicAdd(&bktCnt[t], hist[t]);
}

// ---- A-scan ----------------------------------------------------------------
__global__ void k_bkt_scan(const int* __restrict__ bktCnt, int* __restrict__ bktOff,
                           int* __restrict__ bktCur, int nb, int e) {
    __shared__ int lds[256];
    int t = threadIdx.x;
    int v = (t < nb) ? bktCnt[t] : 0;
    lds[t] = v;
    __syncthreads();
    for (int off = 1; off < 256; off <<= 1) {
        int x = lds[t];
        int y = (t >= off) ? lds[t - off] : 0;
        __syncthreads();
        lds[t] = x + y;
        __syncthreads();
    }
    int ex = lds[t] - v;
    if (t < nb) { bktOff[t] = ex; bktCur[t] = ex; }
    if (t == 0) bktOff[nb] = e;
}

// ---- A2: partition edges into bucket-contiguous (col,row) pairs ------------
__global__ __launch_bounds__(256) void k_bkt_part(const int* __restrict__ row,
                                                  const int* __restrict__ col,
                                                  int* bktCur, int2* __restrict__ ebuf,
                                                  int e, int nb) {
    __shared__ int hist[256];
    __shared__ int base[256];
    __shared__ int lcur[256];
    int t = threadIdx.x;
    hist[t] = 0; lcur[t] = 0;
    __syncthreads();
    int bs = blockIdx.x * EPB;
    int r[EPT], c[EPT], b[EPT];
#pragma unroll
    for (int j = 0; j < EPT; j++) {
        int idx = bs + j * 256 + t;
        if (idx < e) {
            c[j] = col[idx]; r[j] = row[idx]; b[j] = c[j] >> 9;
            atomicAdd(&hist[b[j]], 1);
        } else b[j] = -1;
    }
    __syncthreads();
    if (t < nb && hist[t] > 0) base[t] = atomicAdd(&bktCur[t], hist[t]);
    __syncthreads();
#pragma unroll
    for (int j = 0; j < EPT; j++) {
        if (b[j] >= 0) {
            int lofs = atomicAdd(&lcur[b[j]], 1);
            ebuf[base[b[j]] + lofs] = make_int2(c[j], r[j]);
        }
    }
}

// ---- B1: per-bucket node histogram -> counts + dinv ------------------------
__global__ __launch_bounds__(256) void k_bkt_count(const int2* __restrict__ ebuf,
                                                   const int* __restrict__ bktOff,
                                                   int* __restrict__ counts,
                                                   float* __restrict__ dinv, int n) {
    __shared__ int hist[BSPAN];
    int t = threadIdx.x;
    int bkt = blockIdx.x;
    hist[t] = 0; hist[t + 256] = 0;
    __syncthreads();
    int es = bktOff[bkt], ee = bktOff[bkt + 1];
    for (int e = es + t; e < ee; e += 256)
        atomicAdd(&hist[ebuf[e].x & (BSPAN - 1)], 1);
    __syncthreads();
    int node0 = bkt * BSPAN;
    for (int i = t; i < BSPAN; i += 256) {
        int node = node0 + i;
        if (node < n) {
            int cv = hist[i];
            counts[node] = cv;
            dinv[node] = rsqrtf((float)(cv + 1));
        }
    }
}

// ---- B2: per-bucket CSR fill with LDS cursors ------------------------------
__global__ __launch_bounds__(256) void k_bkt_fill(const int2* __restrict__ ebuf,
                                                  const int* __restrict__ bktOff,
                                                  const int* __restrict__ rowptr,
                                                  int* __restrict__ eSrc, int n) {
    __shared__ int cur[BSPAN];
    int t = threadIdx.x;
    int bkt = blockIdx.x;
    int node0 = bkt * BSPAN;
    for (int i = t; i < BSPAN; i += 256) {
        int node = node0 + i;
        cur[i] = (node < n) ? rowptr[node] : 0;
    }
    __syncthreads();
    int es = bktOff[bkt], ee = bktOff[bkt + 1];
    for (int e = es + t; e < ee; e += 256) {
        int2 p = ebuf[e];
        int slot = atomicAdd(&cur[p.x & (BSPAN - 1)], 1);
        eSrc[slot] = p.y;
    }
}

// ---- prefix scan of counts -> rowptr ---------------------------------------
__global__ void k_scan1(const int* __restrict__ counts, int* __restrict__ rowptr,
                        int* __restrict__ chunkSums, int n) {
    __shared__ int lds[256];
    int b = blockIdx.x, t = threadIdx.x;
    int base = b * 1024 + t * 4;
    int v[4], s = 0;
#pragma unroll
    for (int j = 0; j < 4; j++) {
        v[j] = (base + j < n) ? counts[base + j] : 0;
        s += v[j];
    }
    lds[t] = s;
    __syncthreads();
    for (int off = 1; off < 256; off <<= 1) {
        int x = lds[t];
        int y = (t >= off) ? lds[t - off] : 0;
        __syncthreads();
        lds[t] = x + y;
        __syncthreads();
    }
    int p = lds[t] - s;
#pragma unroll
    for (int j = 0; j < 4; j++) {
        if (base + j < n) rowptr[base + j] = p;
        p += v[j];
    }
    if (t == 255) chunkSums[b] = lds[255];
}

__global__ void k_scan2(const int* __restrict__ chunkSums, int* __restrict__ chunkOffs, int nc) {
    __shared__ int lds[128];
    int t = threadIdx.x;
    int v = (t < nc) ? chunkSums[t] : 0;
    lds[t] = v;
    __syncthreads();
    for (int off = 1; off < 128; off <<= 1) {
        int x = lds[t];
        int y = (t >= off) ? lds[t - off] : 0;
        __syncthreads();
        lds[t] = x + y;
        __syncthreads();
    }
    chunkOffs[t] = lds[t] - v;
}

__global__ void k_scan3(int* rowptr, const int* __restrict__ chunkOffs, int n, int e) {
    int i = blockIdx.x * blockDim.x + threadIdx.x;
    if (i < n) rowptr[i] += chunkOffs[i >> 10];
    if (i == 0) rowptr[n] = e;
}

// ---- xs = f16(dinv (x) x) ---------------------------------------------------
template <int F>
__global__ void k_prescale(const float* __restrict__ x, const float* __restrict__ dinv,
                           f16* __restrict__ xs, int n) {
    constexpr int CH = F / 2;
    int idx = blockIdx.x * blockDim.x + threadIdx.x;
    if (idx >= n * CH) return;
    int node = idx / CH;
    int c = idx - node * CH;
    float d = dinv[node];
    float v[2];
    vload<2>(v, x + (long long)node * F + c * 2);
    f16x2 h;
    h[0] = (f16)(v[0] * d);
    h[1] = (f16)(v[1] * d);
    *reinterpret_cast<f16x2*>(xs + (long long)node * F + c * 2) = h;
}

// ---- gather row-sum (fp16 in, fp32 accum, fp16 out) ------------------------
template <int F>
__global__ __launch_bounds__(256) void k_gather(
        const int* __restrict__ rowptr, const int* __restrict__ eSrc,
        const float* __restrict__ dinv, const f16* __restrict__ hs,
        f16* __restrict__ out, int n) {
    constexpr int CH = F / 2;
    int wave = threadIdx.x >> 6;
    int lane = threadIdx.x & 63;
    int node = blockIdx.x * (blockDim.x >> 6) + wave;
    if (node >= n || lane >= CH) return;

    f16x2 sv = *reinterpret_cast<const f16x2*>(hs + (long long)node * F + lane * 2);
    float acc0 = (float)sv[0], acc1 = (float)sv[1];

    int rs = rowptr[node], re = rowptr[node + 1];
    int e = rs;
    for (; e + 8 <= re; e += 8) {
        int s[8];
#pragma unroll
        for (int u = 0; u < 8; u++) s[u] = eSrc[e + u];
        f16x2 v[8];
#pragma unroll
        for (int u = 0; u < 8; u++)
            v[u] = *reinterpret_cast<const f16x2*>(hs + (long long)s[u] * F + lane * 2);
#pragma unroll
        for (int u = 0; u < 8; u++) {
            acc0 += (float)v[u][0];
            acc1 += (float)v[u][1];
        }
    }
    for (; e < re; e++) {
        int s = eSrc[e];
        f16x2 v = *reinterpret_cast<const f16x2*>(hs + (long long)s * F + lane * 2);
        acc0 += (float)v[0];
        acc1 += (float)v[1];
    }
    float di = dinv[node];
    f16x2 o;
    o[0] = (f16)(acc0 * di);
    o[1] = (f16)(acc1 * di);
    *reinterpret_cast<f16x2*>(out + (long long)node * F + lane * 2) = o;
}

// ---- a_lds staging (shared by gemm kernels) --------------------------------
template <int K, int KV, int KP, int M>
__device__ __forceinline__ void stage_a(const f16* __restrict__ in, f16* a_lds,
                                        int node0, int n, int t) {
    constexpr int GPN = K / KV;
    constexpr int TOT = GPN * M;
    for (int it = 0; it < (TOT + 255) / 256; it++) {
        int f = t + it * 256;
        if (f < TOT) {
            int node = f / GPN;
            int kq = f - node * GPN;
            if (node0 + node < n) {
                if constexpr (KV == 4)
                    *reinterpret_cast<f16x4*>(&a_lds[node * KP + kq * KV]) =
                        *reinterpret_cast<const f16x4*>(in + (long long)(node0 + node) * K + kq * KV);
                else
                    *reinterpret_cast<f16x2*>(&a_lds[node * KP + kq * KV]) =
                        *reinterpret_cast<const f16x2*>(in + (long long)(node0 + node) * K + kq * KV);
            } else {
                for (int j = 0; j < KV; j++) a_lds[node * KP + kq * KV + j] = (f16)0.f;
            }
        }
    }
}

// ---- node-major fp16 GEMM via v_dot2_f32_f16, W prefetch -------------------
// out = f16(dinv * relu(in @ W + b)); Wp is k-pair-packed fp16.
template <int K, int FOUT, int VEC>
__global__ __launch_bounds__(256) void k_gemm_h(
        const f16* __restrict__ in, const f16* __restrict__ Wp,
        const float* __restrict__ bias, const float* __restrict__ dinv,
        f16* __restrict__ outh, int n) {
    constexpr int M = 72, NT = 8;
    constexpr int KV = (K % 4 == 0) ? 4 : 2;
    constexpr int KP = K + KV;
    constexpr int NP = KV / 2;
    static_assert(FOUT / VEC == 27, "FOUT must be 27*VEC");

    __shared__ f16 a_lds[M * KP];
    int t = threadIdx.x;
    int node0 = blockIdx.x * M;
    stage_a<K, KV, KP, M>(in, a_lds, node0, n, t);
    __syncthreads();

    if (t >= 243) return;
    int cg = t % 27;
    int strip = t / 27;

    float acc[NT][VEC];
#pragma unroll
    for (int i = 0; i < NT; i++)
#pragma unroll
        for (int j = 0; j < VEC; j++) acc[i][j] = 0.f;

    const f16x2* wpp = reinterpret_cast<const f16x2*>(Wp) + cg * VEC;

    f16x2 wc[NP][VEC];
#pragma unroll
    for (int p = 0; p < NP; p++) vload_p<VEC>(wc[p], wpp + (size_t)p * FOUT);

    for (int k0 = 0; k0 < K; k0 += KV) {
        f16x2 wn[NP][VEC];
        bool more = (k0 + KV < K);
        if (more) {
            int kpn = (k0 + KV) >> 1;
#pragma unroll
            for (int p = 0; p < NP; p++) vload_p<VEC>(wn[p], wpp + (size_t)(kpn + p) * FOUT);
        }
        f16x2 av[NT][NP];
#pragma unroll
        for (int i = 0; i < NT; i++) {
            if constexpr (KV == 4)
                *reinterpret_cast<float2*>(av[i]) =
                    *reinterpret_cast<const float2*>(&a_lds[(strip + 9 * i) * KP + k0]);
            else
                av[i][0] = *reinterpret_cast<const f16x2*>(&a_lds[(strip + 9 * i) * KP + k0]);
        }
#pragma unroll
        for (int p = 0; p < NP; p++)
#pragma unroll
            for (int i = 0; i < NT; i++)
#pragma unroll
                for (int j = 0; j < VEC; j++)
                    acc[i][j] = __builtin_amdgcn_fdot2(av[i][p], wc[p][j], acc[i][j], false);
        if (more) {
#pragma unroll
            for (int p = 0; p < NP; p++)
#pragma unroll
                for (int j = 0; j < VEC; j++) wc[p][j] = wn[p][j];
        }
    }

    float bv[VEC];
    vload<VEC>(bv, bias + cg * VEC);
#pragma unroll
    for (int i = 0; i < NT; i++) {
        int node = node0 + strip + 9 * i;
        if (node >= n) continue;
        float sc = dinv[node];
        float o[VEC];
#pragma unroll
        for (int j = 0; j < VEC; j++)
            o[j] = fmaxf(acc[i][j] + bv[j], 0.f) * sc;
        if constexpr (VEC == 2) {
            f16x2 h; h[0] = (f16)o[0]; h[1] = (f16)o[1];
            *reinterpret_cast<f16x2*>(outh + (long long)node * FOUT + cg * VEC) = h;
        } else {
            f16x4 h;
#pragma unroll
            for (int j = 0; j < 4; j++) h[j] = (f16)o[j];
            *reinterpret_cast<f16x4*>(outh + (long long)node * FOUT + cg * VEC) = h;
        }
    }
}

// ---- layer-3 dot2 GEMM with LDS-staged fused mean-pool ---------------------
template <int K, int FOUT, int VEC>
__global__ __launch_bounds__(256) void k_gemm_pool(
        const f16* __restrict__ in, const f16* __restrict__ Wp,
        const float* __restrict__ bias, const int* __restrict__ batch,
        float* __restrict__ psum, int n) {
    constexpr int M = 72, NT = 8;
    constexpr int KV = (K % 4 == 0) ? 4 : 2;
    constexpr int KP = K + KV;
    constexpr int NP = KV / 2;
    constexpr int NSLOT = 4;
    static_assert(FOUT / VEC == 27, "FOUT must be 27*VEC");
    static_assert(M * KP * 2 >= NSLOT * FOUT * 4, "psum_l must fit in a_lds");

    __shared__ f16 a_lds[M * KP];
    int t = threadIdx.x;
    int node0 = blockIdx.x * M;
    stage_a<K, KV, KP, M>(in, a_lds, node0, n, t);
    __syncthreads();

    bool active = (t < 243);
    int cg = t % 27;
    int strip = t / 27;

    float acc[NT][VEC];
#pragma unroll
    for (int i = 0; i < NT; i++)
#pragma unroll
        for (int j = 0; j < VEC; j++) acc[i][j] = 0.f;

    if (active) {
        const f16x2* wpp = reinterpret_cast<const f16x2*>(Wp) + cg * VEC;
        f16x2 wc[NP][VEC];
#pragma unroll
        for (int p = 0; p < NP; p++) vload_p<VEC>(wc[p], wpp + (size_t)p * FOUT);

        for (int k0 = 0; k0 < K; k0 += KV) {
            f16x2 wn[NP][VEC];
            bool more = (k0 + KV < K);
            if (more) {
                int kpn = (k0 + KV) >> 1;
#pragma unroll
                for (int p = 0; p < NP; p++) vload_p<VEC>(wn[p], wpp + (size_t)(kpn + p) * FOUT);
            }
            f16x2 av[NT][NP];
#pragma unroll
            for (int i = 0; i < NT; i++) {
                if constexpr (KV == 4)
                    *reinterpret_cast<float2*>(av[i]) =
                        *reinterpret_cast<const float2*>(&a_lds[(strip + 9 * i) * KP + k0]);
                else
                    av[i][0] = *reinterpret_cast<const f16x2*>(&a_lds[(strip + 9 * i) * KP + k0]);
            }
#pragma unroll
            for (int p = 0; p < NP; p++)
#pragma unroll
                for (int i = 0; i < NT; i++)
#pragma unroll
                    for (int j = 0; j < VEC; j++)
                        acc[i][j] = __builtin_amdgcn_fdot2(av[i][p], wc[p][j], acc[i][j], false);
            if (more) {
#pragma unroll
                for (int p = 0; p < NP; p++)
#pragma unroll
                    for (int j = 0; j < VEC; j++) wc[p][j] = wn[p][j];
            }
        }
    }

    // ---- LDS-staged pool epilogue (reuse a_lds as float psum_l) ----
    __syncthreads();
    float* psum_l = reinterpret_cast<float*>(a_lds);
    for (int i = t; i < NSLOT * FOUT; i += 256) psum_l[i] = 0.f;
    __syncthreads();

    int g0 = batch[node0];
    if (active) {
        float bv[VEC];
        vload<VEC>(bv, bias + cg * VEC);
        float gacc[VEC];
#pragma unroll
        for (int j = 0; j < VEC; j++) gacc[j] = 0.f;
        int gcur = -1;
#pragma unroll
        for (int i = 0; i < NT; i++) {
            int node = node0 + strip + 9 * i;
            if (node >= n) break;
            int g = batch[node];
            if (g != gcur) {
                if (gcur >= 0) {
                    int slot = gcur - g0;
                    if (slot < NSLOT) {
#pragma unroll
                        for (int j = 0; j < VEC; j++)
                            atomicAdd(&psum_l[slot * FOUT + cg * VEC + j], gacc[j]);
                    } else {
#pragma unroll
                        for (int j = 0; j < VEC; j++)
                            atomicAdd(&psum[gcur * FOUT + cg * VEC + j], gacc[j]);
                    }
                }
                gcur = g;
#pragma unroll
                for (int j = 0; j < VEC; j++) gacc[j] = 0.f;
            }
#pragma unroll
            for (int j = 0; j < VEC; j++)
                gacc[j] += fmaxf(acc[i][j] + bv[j], 0.f);
        }
        if (gcur >= 0) {
            int slot = gcur - g0;
            if (slot < NSLOT) {
#pragma unroll
                for (int j = 0; j < VEC; j++)
                    atomicAdd(&psum_l[slot * FOUT + cg * VEC + j], gacc[j]);
            } else {
#pragma unroll
                for (int j = 0; j < VEC; j++)
                    atomicAdd(&psum[gcur * FOUT + cg * VEC + j], gacc[j]);
            }
        }
    }
    __syncthreads();

    int lastNode = node0 + M - 1;
    if (lastNode >= n) lastNode = n - 1;
    int nslots = batch[lastNode] - g0 + 1;
    if (nslots > NSLOT) nslots = NSLOT;
    for (int f = t; f < nslots * FOUT; f += 256) {
        float v = psum_l[f];
        if (v != 0.f) atomicAdd(&psum[(g0 + f / FOUT) * FOUT + (f % FOUT)], v);
    }
}

// ---- per-graph boundaries (batch sorted ascending) -------------------------
__global__ void k_init_start(int* start, int n, int g) {
    int i = blockIdx.x * blockDim.x + threadIdx.x;
    if (i <= g) start[i] = n;
}
__global__ void k_find_start(const int* __restrict__ batch, int* start, int n) {
    int i = blockIdx.x * blockDim.x + threadIdx.x;
    if (i >= n) return;
    int b = batch[i];
    int bp = (i == 0) ? -1 : batch[i - 1];
    for (int g = bp + 1; g <= b; g++) start[g] = i;
}

// ---- FC layers (fc1 folds the mean divide) ---------------------------------
__global__ void k_fc1(const float* __restrict__ P, const int* __restrict__ start,
                      const float* __restrict__ W, const float* __restrict__ bias,
                      float* __restrict__ out) {
    int row = blockIdx.x >> 2;
    int o = (blockIdx.x & 3) * 256 + threadIdx.x;
    int cnt = start[row + 1] - start[row];
    float scale = 1.0f / fmaxf((float)cnt, 1.0f);
    __shared__ float prow[216];
    if (threadIdx.x < 216) prow[threadIdx.x] = P[row * 216 + threadIdx.x] * scale;
    __syncthreads();
    float acc = bias[o];
    for (int k = 0; k < 216; k++) acc += prow[k] * W[k * 1024 + o];
    out[row * 1024 + o] = fmaxf(acc, 0.f);
}
__global__ void k_fc2(const float* __restrict__ G, const float* __restrict__ W,
                      const float* __restrict__ bias, float* __restrict__ out) {
    int row = blockIdx.x;
    int o = threadIdx.x;  // 128
    __shared__ float grow[1024];
    for (int k = threadIdx.x; k < 1024; k += 128) grow[k] = G[row * 1024 + k];
    __syncthreads();
    float acc = bias[o];
    for (int k = 0; k < 1024; k++) acc += grow[k] * W[k * 128 + o];
    out[row * 128 + o] = acc;
}

// ---------------------------------------------------------------------------
extern "C" void kernel_launch(void* const* d_in, const int* in_sizes, int n_in,
                              void* d_out, int out_size, void* d_ws, size_t ws_size,
                              hipStream_t stream) {
    const float* x     = (const float*)d_in[0];
    const int*   ei    = (const int*)d_in[1];
    const int*   batch = (const int*)d_in[2];
    const float* W1  = (const float*)d_in[3];
    const float* b1  = (const float*)d_in[4];
    const float* W2  = (const float*)d_in[5];
    const float* b2  = (const float*)d_in[6];
    const float* W3  = (const float*)d_in[7];
    const float* b3  = (const float*)d_in[8];
    const float* Wf1 = (const float*)d_in[9];
    const float* bf1 = (const float*)d_in[10];
    const float* Wf2 = (const float*)d_in[11];
    const float* bf2 = (const float*)d_in[12];
    float* out = (float*)d_out;

    const int N = in_sizes[0] / 54;   // 100000
    const int E = in_sizes[1] / 2;    // 1600000
    const int G = 256;
    const int* row = ei;
    const int* col = ei + E;
    const int NCHUNK = cdiv(N, 1024);
    const int NB = cdiv(N, BSPAN);
    const int NBLK_A = cdiv(E, EPB);

    // workspace carve-up (256B aligned)
    char* ws = (char*)d_ws;
    size_t off = 0;
    auto carve = [&](size_t bytes) {
        void* p = ws + off;
        off += (bytes + 255) & ~(size_t)255;
        return p;
    };
    int*   counts    = (int*)carve((size_t)N * 4);
    int*   rowptr    = (int*)carve((size_t)(N + 1) * 4);
    int*   chunkSums = (int*)carve(128 * 4);
    int*   chunkOffs = (int*)carve(128 * 4);
    int*   bktCnt    = (int*)carve(256 * 4);
    int*   bktOff    = (int*)carve(257 * 4);
    int*   bktCur    = (int*)carve(256 * 4);
    int*   eSrc      = (int*)carve((size_t)E * 4);
    float* dinv      = (float*)carve((size_t)N * 4);
    f16*   xs        = (f16*)carve((size_t)N * 54 * 2);
    f16*   hsbuf     = (f16*)carve((size_t)N * 108 * 2);
    f16*   bufA      = (f16*)carve((size_t)N * 108 * 2);
    int2*  ebuf      = (int2*)carve((size_t)E * 8);
    float* psum      = (float*)carve((size_t)G * 216 * 4);
    float* gbuf      = (float*)carve((size_t)G * 1024 * 4);
    int*   start     = (int*)carve((size_t)(G + 1) * 4);
    f16*   w1p       = (f16*)carve((size_t)54 * 54 * 2);
    f16*   w2p       = (f16*)carve((size_t)54 * 108 * 2);
    f16*   w3p       = (f16*)carve((size_t)108 * 216 * 2);

    const int T = 256;

    // ---- weight packing (fp32 -> k-pair-interleaved fp16) ----
    k_wpack<<<cdiv(54 * 54, T), T, 0, stream>>>(W1, w1p, 54, 54);
    k_wpack<<<cdiv(54 * 108, T), T, 0, stream>>>(W2, w2p, 54, 108);
    k_wpack<<<cdiv(108 * 216, T), T, 0, stream>>>(W3, w3p, 108, 216);

    // ---- bucketed CSR build ----
    k_zero2<<<cdiv(G * 216, T), T, 0, stream>>>(psum, G * 216, bktCnt, 256);
    k_bkt_hist<<<NBLK_A, 256, 0, stream>>>(col, bktCnt, E, NB);
    k_bkt_scan<<<1, 256, 0, stream>>>(bktCnt, bktOff, bktCur, NB, E);
    k_bkt_part<<<NBLK_A, 256, 0, stream>>>(row, col, bktCur, ebuf, E, NB);
    k_bkt_count<<<NB, 256, 0, stream>>>(ebuf, bktOff, counts, dinv, N);
    k_scan1<<<NCHUNK, 256, 0, stream>>>(counts, rowptr, chunkSums, N);
    k_scan2<<<1, 128, 0, stream>>>(chunkSums, chunkOffs, NCHUNK);
    k_scan3<<<cdiv(N, T), T, 0, stream>>>(rowptr, chunkOffs, N, E);
    k_bkt_fill<<<NB, 256, 0, stream>>>(ebuf, bktOff, rowptr, eSrc, N);
    k_prescale<54><<<cdiv(N * 27, T), T, 0, stream>>>(x, dinv, xs, N);

    // ---- graph boundaries ----
    k_init_start<<<cdiv(G + 1, T), T, 0, stream>>>(start, N, G);
    k_find_start<<<cdiv(N, T), T, 0, stream>>>(batch, start, N);

    const int GB = cdiv(N, 72);

    // ---- layer 1 ----
    k_gather<54><<<cdiv(N, 4), 256, 0, stream>>>(rowptr, eSrc, dinv, xs, bufA, N);
    k_gemm_h<54, 54, 2><<<GB, 256, 0, stream>>>(bufA, w1p, b1, dinv, hsbuf, N);

    // ---- layer 2 ----
    k_gather<54><<<cdiv(N, 4), 256, 0, stream>>>(rowptr, eSrc, dinv, hsbuf, bufA, N);
    k_gemm_h<54, 108, 4><<<GB, 256, 0, stream>>>(bufA, w2p, b2, dinv, hsbuf, N);

    // ---- layer 3 (fused pool) ----
    k_gather<108><<<cdiv(N, 4), 256, 0, stream>>>(rowptr, eSrc, dinv, hsbuf, bufA, N);
    k_gemm_pool<108, 216, 8><<<GB, 256, 0, stream>>>(bufA, w3p, b3, batch, psum, N);

    // ---- FC head ----
    k_fc1<<<G * 4, T, 0, stream>>>(psum, start, Wf1, bf1, gbuf);
    k_fc2<<<G, 128, 0, stream>>>(gbuf, Wf2, bf2, out);
}

// Round 13
// 483.956 us; speedup vs baseline: 1.1906x; 1.1906x over previous
//
#include <hip/hip_runtime.h>

// ---------------------------------------------------------------------------
// ProteinGCNNet: 3x GCNConv + mean-pool + 2 FC layers.
// Round 13: MFMA (v_mfma_f32_16x16x32_f16) node GEMMs. Wave = 16-node x
// 16-channel C tile; A node-major fp16 in LDS (b128 frag reads, +8 pad);
// W device-packed into B-fragment order (m92 gemm_bt verified layout).
// LDS-staged fused pool kept. Bucketed CSR + fp16 gathers kept.
// ---------------------------------------------------------------------------

typedef _Float16 f16;
typedef _Float16 f16x2 __attribute__((ext_vector_type(2)));
typedef _Float16 f16x4 __attribute__((ext_vector_type(4)));
typedef _Float16 f16x8 __attribute__((ext_vector_type(8)));
typedef float f32x4 __attribute__((ext_vector_type(4)));

static __host__ __device__ inline int cdiv(int a, int b) { return (a + b - 1) / b; }

constexpr int BSPAN = 512;
constexpr int EPB   = 4096;
constexpr int EPT   = EPB / 256;

template <int V>
__device__ __forceinline__ void vload(float* d, const float* s) {
    if constexpr (V == 1) { d[0] = s[0]; }
    else if constexpr (V == 2) { float2 t = *reinterpret_cast<const float2*>(s); d[0] = t.x; d[1] = t.y; }
    else { float4 t = *reinterpret_cast<const float4*>(s); d[0] = t.x; d[1] = t.y; d[2] = t.z; d[3] = t.w; }
}

// ---- MFMA B-fragment weight pack -------------------------------------------
// Wb[((nt*KT + kt)*64 + lane)*8 + j] = f16(W[kt*32 + (lane>>4)*8 + j][nt*16 + (lane&15)])
__global__ void k_wpackm(const float* __restrict__ W, f16* __restrict__ Wb,
                         int K, int F, int KT, int NT) {
    int idx = blockIdx.x * blockDim.x + threadIdx.x;
    int total = NT * KT * 512;
    if (idx >= total) return;
    int j = idx & 7;
    int lane = (idx >> 3) & 63;
    int fi = idx >> 9;
    int kt = fi % KT;
    int nt = fi / KT;
    int k = kt * 32 + (lane >> 4) * 8 + j;
    int nn = nt * 16 + (lane & 15);
    Wb[idx] = (k < K && nn < F) ? (f16)W[k * F + nn] : (f16)0.f;
}

// ---- zero psum (float) + bktCnt (int) --------------------------------------
__global__ void k_zero2(float* pf, int nf, int* pi, int ni) {
    int i = blockIdx.x * blockDim.x + threadIdx.x;
    if (i < nf) pf[i] = 0.f;
    if (i < ni) pi[i] = 0;
}

// ---- A1: per-block LDS bucket histogram ------------------------------------
__global__ __launch_bounds__(256) void k_bkt_hist(const int* __restrict__ col,
                                                  int* bktCnt, int e, int nb) {
    __shared__ int hist[256];
    int t = threadIdx.x;
    hist[t] = 0;
    __syncthreads();
    int base = blockIdx.x * EPB;
#pragma unroll
    for (int j = 0; j < EPT; j++) {
        int idx = base + j * 256 + t;
        if (idx < e) atomicAdd(&hist[col[idx] >> 9], 1);
    }
    __syncthreads();
    if (t < nb && hist[t] > 0) atomicAdd(&bktCnt[t], hist[t]);
}

// ---- A-scan ----------------------------------------------------------------
__global__ void k_bkt_scan(const int* __restrict__ bktCnt, int* __restrict__ bktOff,
                           int* __restrict__ bktCur, int nb, int e) {
    __shared__ int lds[256];
    int t = threadIdx.x;
    int v = (t < nb) ? bktCnt[t] : 0;
    lds[t] = v;
    __syncthreads();
    for (int off = 1; off < 256; off <<= 1) {
        int x = lds[t];
        int y = (t >= off) ? lds[t - off] : 0;
        __syncthreads();
        lds[t] = x + y;
        __syncthreads();
    }
    int ex = lds[t] - v;
    if (t < nb) { bktOff[t] = ex; bktCur[t] = ex; }
    if (t == 0) bktOff[nb] = e;
}

// ---- A2: partition edges into bucket-contiguous (col,row) pairs ------------
__global__ __launch_bounds__(256) void k_bkt_part(const int* __restrict__ row,
                                                  const int* __restrict__ col,
                                                  int* bktCur, int2* __restrict__ ebuf,
                                                  int e, int nb) {
    __shared__ int hist[256];
    __shared__ int base[256];
    __shared__ int lcur[256];
    int t = threadIdx.x;
    hist[t] = 0; lcur[t] = 0;
    __syncthreads();
    int bs = blockIdx.x * EPB;
    int r[EPT], c[EPT], b[EPT];
#pragma unroll
    for (int j = 0; j < EPT; j++) {
        int idx = bs + j * 256 + t;
        if (idx < e) {
            c[j] = col[idx]; r[j] = row[idx]; b[j] = c[j] >> 9;
            atomicAdd(&hist[b[j]], 1);
        } else b[j] = -1;
    }
    __syncthreads();
    if (t < nb && hist[t] > 0) base[t] = atomicAdd(&bktCur[t], hist[t]);
    __syncthreads();
#pragma unroll
    for (int j = 0; j < EPT; j++) {
        if (b[j] >= 0) {
            int lofs = atomicAdd(&lcur[b[j]], 1);
            ebuf[base[b[j]] + lofs] = make_int2(c[j], r[j]);
        }
    }
}

// ---- B1: per-bucket node histogram -> counts + dinv ------------------------
__global__ __launch_bounds__(256) void k_bkt_count(const int2* __restrict__ ebuf,
                                                   const int* __restrict__ bktOff,
                                                   int* __restrict__ counts,
                                                   float* __restrict__ dinv, int n) {
    __shared__ int hist[BSPAN];
    int t = threadIdx.x;
    int bkt = blockIdx.x;
    hist[t] = 0; hist[t + 256] = 0;
    __syncthreads();
    int es = bktOff[bkt], ee = bktOff[bkt + 1];
    for (int e = es + t; e < ee; e += 256)
        atomicAdd(&hist[ebuf[e].x & (BSPAN - 1)], 1);
    __syncthreads();
    int node0 = bkt * BSPAN;
    for (int i = t; i < BSPAN; i += 256) {
        int node = node0 + i;
        if (node < n) {
            int cv = hist[i];
            counts[node] = cv;
            dinv[node] = rsqrtf((float)(cv + 1));
        }
    }
}

// ---- B2: per-bucket CSR fill with LDS cursors ------------------------------
__global__ __launch_bounds__(256) void k_bkt_fill(const int2* __restrict__ ebuf,
                                                  const int* __restrict__ bktOff,
                                                  const int* __restrict__ rowptr,
                                                  int* __restrict__ eSrc, int n) {
    __shared__ int cur[BSPAN];
    int t = threadIdx.x;
    int bkt = blockIdx.x;
    int node0 = bkt * BSPAN;
    for (int i = t; i < BSPAN; i += 256) {
        int node = node0 + i;
        cur[i] = (node < n) ? rowptr[node] : 0;
    }
    __syncthreads();
    int es = bktOff[bkt], ee = bktOff[bkt + 1];
    for (int e = es + t; e < ee; e += 256) {
        int2 p = ebuf[e];
        int slot = atomicAdd(&cur[p.x & (BSPAN - 1)], 1);
        eSrc[slot] = p.y;
    }
}

// ---- prefix scan of counts -> rowptr ---------------------------------------
__global__ void k_scan1(const int* __restrict__ counts, int* __restrict__ rowptr,
                        int* __restrict__ chunkSums, int n) {
    __shared__ int lds[256];
    int b = blockIdx.x, t = threadIdx.x;
    int base = b * 1024 + t * 4;
    int v[4], s = 0;
#pragma unroll
    for (int j = 0; j < 4; j++) {
        v[j] = (base + j < n) ? counts[base + j] : 0;
        s += v[j];
    }
    lds[t] = s;
    __syncthreads();
    for (int off = 1; off < 256; off <<= 1) {
        int x = lds[t];
        int y = (t >= off) ? lds[t - off] : 0;
        __syncthreads();
        lds[t] = x + y;
        __syncthreads();
    }
    int p = lds[t] - s;
#pragma unroll
    for (int j = 0; j < 4; j++) {
        if (base + j < n) rowptr[base + j] = p;
        p += v[j];
    }
    if (t == 255) chunkSums[b] = lds[255];
}

__global__ void k_scan2(const int* __restrict__ chunkSums, int* __restrict__ chunkOffs, int nc) {
    __shared__ int lds[128];
    int t = threadIdx.x;
    int v = (t < nc) ? chunkSums[t] : 0;
    lds[t] = v;
    __syncthreads();
    for (int off = 1; off < 128; off <<= 1) {
        int x = lds[t];
        int y = (t >= off) ? lds[t - off] : 0;
        __syncthreads();
        lds[t] = x + y;
        __syncthreads();
    }
    chunkOffs[t] = lds[t] - v;
}

__global__ void k_scan3(int* rowptr, const int* __restrict__ chunkOffs, int n, int e) {
    int i = blockIdx.x * blockDim.x + threadIdx.x;
    if (i < n) rowptr[i] += chunkOffs[i >> 10];
    if (i == 0) rowptr[n] = e;
}

// ---- xs = f16(dinv (x) x) ---------------------------------------------------
template <int F>
__global__ void k_prescale(const float* __restrict__ x, const float* __restrict__ dinv,
                           f16* __restrict__ xs, int n) {
    constexpr int CH = F / 2;
    int idx = blockIdx.x * blockDim.x + threadIdx.x;
    if (idx >= n * CH) return;
    int node = idx / CH;
    int c = idx - node * CH;
    float d = dinv[node];
    float v[2];
    vload<2>(v, x + (long long)node * F + c * 2);
    f16x2 h;
    h[0] = (f16)(v[0] * d);
    h[1] = (f16)(v[1] * d);
    *reinterpret_cast<f16x2*>(xs + (long long)node * F + c * 2) = h;
}

// ---- gather row-sum (fp16 in, fp32 accum, fp16 out) ------------------------
template <int F>
__global__ __launch_bounds__(256) void k_gather(
        const int* __restrict__ rowptr, const int* __restrict__ eSrc,
        const float* __restrict__ dinv, const f16* __restrict__ hs,
        f16* __restrict__ out, int n) {
    constexpr int CH = F / 2;
    int wave = threadIdx.x >> 6;
    int lane = threadIdx.x & 63;
    int node = blockIdx.x * (blockDim.x >> 6) + wave;
    if (node >= n || lane >= CH) return;

    f16x2 sv = *reinterpret_cast<const f16x2*>(hs + (long long)node * F + lane * 2);
    float acc0 = (float)sv[0], acc1 = (float)sv[1];

    int rs = rowptr[node], re = rowptr[node + 1];
    int e = rs;
    for (; e + 8 <= re; e += 8) {
        int s[8];
#pragma unroll
        for (int u = 0; u < 8; u++) s[u] = eSrc[e + u];
        f16x2 v[8];
#pragma unroll
        for (int u = 0; u < 8; u++)
            v[u] = *reinterpret_cast<const f16x2*>(hs + (long long)s[u] * F + lane * 2);
#pragma unroll
        for (int u = 0; u < 8; u++) {
            acc0 += (float)v[u][0];
            acc1 += (float)v[u][1];
        }
    }
    for (; e < re; e++) {
        int s = eSrc[e];
        f16x2 v = *reinterpret_cast<const f16x2*>(hs + (long long)s * F + lane * 2);
        acc0 += (float)v[0];
        acc1 += (float)v[1];
    }
    float di = dinv[node];
    f16x2 o;
    o[0] = (f16)(acc0 * di);
    o[1] = (f16)(acc1 * di);
    *reinterpret_cast<f16x2*>(out + (long long)node * F + lane * 2) = o;
}

// ---- MFMA node GEMM --------------------------------------------------------
// Block = 4 waves x 64 nodes; wave w owns nodes [node0+16w, +16).
// A staged node-major fp16 in LDS, stride KP=KTILES*32+8 (2-way banks, free).
// Wb is B-fragment packed. POOL: fused per-graph mean-pool via LDS psum.
// !POOL: out = f16(dinv * relu(A@W + b)).
template <int KTILES, int NTILES, int K, int FOUT, bool POOL>
__global__ __launch_bounds__(256) void k_gemm_mfma(
        const f16* __restrict__ in, const f16* __restrict__ Wb,
        const float* __restrict__ bias, const float* __restrict__ dinv,
        const int* __restrict__ batch, f16* __restrict__ outh,
        float* __restrict__ psum, int n) {
    constexpr int KPAD = KTILES * 32;
    constexpr int KP   = KPAD + 8;      // f16 stride
    constexpr int PPR  = KPAD / 2;      // f16x2 pairs per row
    constexpr int NSLOT = 4;

    __shared__ f16 a_lds[64 * KP];
    __shared__ float psum_l[POOL ? NSLOT * FOUT : 1];

    int t = threadIdx.x;
    int node0 = blockIdx.x * 64;

    // ---- stage A (zero-padded) ----
    const f16x2* inp = reinterpret_cast<const f16x2*>(in);
    constexpr int TOTP = 64 * PPR;
    for (int f = t; f < TOTP; f += 256) {
        int node = f / PPR;
        int kp = f - node * PPR;
        f16x2 v = {};
        if (node0 + node < n && kp < K / 2)
            v = inp[(long long)(node0 + node) * (K / 2) + kp];
        *reinterpret_cast<f16x2*>(&a_lds[node * KP + kp * 2]) = v;
    }
    if (POOL) {
        for (int i = t; i < NSLOT * FOUT; i += 256) psum_l[i] = 0.f;
    }
    __syncthreads();

    int w = t >> 6;
    int lane = t & 63;
    int quad = lane >> 4;
    int col = lane & 15;

    // A fragments: A[m=lane&15][k=quad*8+j]
    f16x8 afr[KTILES];
#pragma unroll
    for (int kt = 0; kt < KTILES; kt++)
        afr[kt] = *reinterpret_cast<const f16x8*>(
            &a_lds[(16 * w + col) * KP + kt * 32 + quad * 8]);

    // per-C-row node info (row = quad*4 + reg)
    int nodeC = node0 + 16 * w + quad * 4;
    float dv[4];
    int gb[4];
#pragma unroll
    for (int r = 0; r < 4; r++) {
        int nd = nodeC + r;
        bool valid = nd < n;
        if (POOL) {
            gb[r] = valid ? batch[nd] : -1;
            dv[r] = 0.f;
        } else {
            dv[r] = valid ? dinv[nd] : 0.f;
            gb[r] = -1;
        }
    }
    int g0 = POOL ? batch[node0] : 0;

    const f16x8* wb = reinterpret_cast<const f16x8*>(Wb);
#pragma unroll
    for (int nt = 0; nt < NTILES; nt++) {
        f16x8 bfr[KTILES];
#pragma unroll
        for (int kt = 0; kt < KTILES; kt++)
            bfr[kt] = wb[(nt * KTILES + kt) * 64 + lane];
        f32x4 acc = {0.f, 0.f, 0.f, 0.f};
#pragma unroll
        for (int kt = 0; kt < KTILES; kt++)
            acc = __builtin_amdgcn_mfma_f32_16x16x32_f16(afr[kt], bfr[kt], acc, 0, 0, 0);

        int ch = nt * 16 + col;
        if (ch < FOUT) {
            float bval = bias[ch];
            if (POOL) {
                if (gb[0] == gb[3] && gb[0] >= 0) {
                    // all 4 rows same graph (batch sorted): one atomic
                    float s = fmaxf(acc[0] + bval, 0.f) + fmaxf(acc[1] + bval, 0.f)
                            + fmaxf(acc[2] + bval, 0.f) + fmaxf(acc[3] + bval, 0.f);
                    int slot = gb[0] - g0;
                    if (slot < NSLOT) atomicAdd(&psum_l[slot * FOUT + ch], s);
                    else atomicAdd(&psum[gb[0] * FOUT + ch], s);
                } else {
#pragma unroll
                    for (int r = 0; r < 4; r++) {
                        if (gb[r] < 0) continue;
                        float v = fmaxf(acc[r] + bval, 0.f);
                        int slot = gb[r] - g0;
                        if (slot < NSLOT) atomicAdd(&psum_l[slot * FOUT + ch], v);
                        else atomicAdd(&psum[gb[r] * FOUT + ch], v);
                    }
                }
            } else {
#pragma unroll
                for (int r = 0; r < 4; r++) {
                    int nd = nodeC + r;
                    if (nd < n)
                        outh[(long long)nd * FOUT + ch] =
                            (f16)(fmaxf(acc[r] + bval, 0.f) * dv[r]);
                }
            }
        }
    }

    if (POOL) {
        __syncthreads();
        int lastNode = node0 + 63;
        if (lastNode >= n) lastNode = n - 1;
        int nsl = batch[lastNode] - g0 + 1;
        if (nsl > NSLOT) nsl = NSLOT;
        for (int f = t; f < nsl * FOUT; f += 256) {
            float v = psum_l[f];
            if (v != 0.f) atomicAdd(&psum[(g0 + f / FOUT) * FOUT + (f % FOUT)], v);
        }
    }
}

// ---- per-graph boundaries (batch sorted ascending) -------------------------
__global__ void k_init_start(int* start, int n, int g) {
    int i = blockIdx.x * blockDim.x + threadIdx.x;
    if (i <= g) start[i] = n;
}
__global__ void k_find_start(const int* __restrict__ batch, int* start, int n) {
    int i = blockIdx.x * blockDim.x + threadIdx.x;
    if (i >= n) return;
    int b = batch[i];
    int bp = (i == 0) ? -1 : batch[i - 1];
    for (int g = bp + 1; g <= b; g++) start[g] = i;
}

// ---- FC layers (fc1 folds the mean divide) ---------------------------------
__global__ void k_fc1(const float* __restrict__ P, const int* __restrict__ start,
                      const float* __restrict__ W, const float* __restrict__ bias,
                      float* __restrict__ out) {
    int row = blockIdx.x >> 2;
    int o = (blockIdx.x & 3) * 256 + threadIdx.x;
    int cnt = start[row + 1] - start[row];
    float scale = 1.0f / fmaxf((float)cnt, 1.0f);
    __shared__ float prow[216];
    if (threadIdx.x < 216) prow[threadIdx.x] = P[row * 216 + threadIdx.x] * scale;
    __syncthreads();
    float acc = bias[o];
    for (int k = 0; k < 216; k++) acc += prow[k] * W[k * 1024 + o];
    out[row * 1024 + o] = fmaxf(acc, 0.f);
}
__global__ void k_fc2(const float* __restrict__ G, const float* __restrict__ W,
                      const float* __restrict__ bias, float* __restrict__ out) {
    int row = blockIdx.x;
    int o = threadIdx.x;  // 128
    __shared__ float grow[1024];
    for (int k = threadIdx.x; k < 1024; k += 128) grow[k] = G[row * 1024 + k];
    __syncthreads();
    float acc = bias[o];
    for (int k = 0; k < 1024; k++) acc += grow[k] * W[k * 128 + o];
    out[row * 128 + o] = acc;
}

// ---------------------------------------------------------------------------
extern "C" void kernel_launch(void* const* d_in, const int* in_sizes, int n_in,
                              void* d_out, int out_size, void* d_ws, size_t ws_size,
                              hipStream_t stream) {
    const float* x     = (const float*)d_in[0];
    const int*   ei    = (const int*)d_in[1];
    const int*   batch = (const int*)d_in[2];
    const float* W1  = (const float*)d_in[3];
    const float* b1  = (const float*)d_in[4];
    const float* W2  = (const float*)d_in[5];
    const float* b2  = (const float*)d_in[6];
    const float* W3  = (const float*)d_in[7];
    const float* b3  = (const float*)d_in[8];
    const float* Wf1 = (const float*)d_in[9];
    const float* bf1 = (const float*)d_in[10];
    const float* Wf2 = (const float*)d_in[11];
    const float* bf2 = (const float*)d_in[12];
    float* out = (float*)d_out;

    const int N = in_sizes[0] / 54;   // 100000
    const int E = in_sizes[1] / 2;    // 1600000
    const int G = 256;
    const int* row = ei;
    const int* col = ei + E;
    const int NCHUNK = cdiv(N, 1024);
    const int NB = cdiv(N, BSPAN);
    const int NBLK_A = cdiv(E, EPB);

    // workspace carve-up (256B aligned)
    char* ws = (char*)d_ws;
    size_t off = 0;
    auto carve = [&](size_t bytes) {
        void* p = ws + off;
        off += (bytes + 255) & ~(size_t)255;
        return p;
    };
    int*   counts    = (int*)carve((size_t)N * 4);
    int*   rowptr    = (int*)carve((size_t)(N + 1) * 4);
    int*   chunkSums = (int*)carve(128 * 4);
    int*   chunkOffs = (int*)carve(128 * 4);
    int*   bktCnt    = (int*)carve(256 * 4);
    int*   bktOff    = (int*)carve(257 * 4);
    int*   bktCur    = (int*)carve(256 * 4);
    int*   eSrc      = (int*)carve((size_t)E * 4);
    float* dinv      = (float*)carve((size_t)N * 4);
    f16*   xs        = (f16*)carve((size_t)N * 54 * 2);
    f16*   hsbuf     = (f16*)carve((size_t)N * 108 * 2);
    f16*   bufA      = (f16*)carve((size_t)N * 108 * 2);
    int2*  ebuf      = (int2*)carve((size_t)E * 8);
    float* psum      = (float*)carve((size_t)G * 216 * 4);
    float* gbuf      = (float*)carve((size_t)G * 1024 * 4);
    int*   start     = (int*)carve((size_t)(G + 1) * 4);
    f16*   w1b       = (f16*)carve((size_t)4 * 2 * 512 * 2);    // NT=4,KT=2
    f16*   w2b       = (f16*)carve((size_t)7 * 2 * 512 * 2);    // NT=7,KT=2
    f16*   w3b       = (f16*)carve((size_t)14 * 4 * 512 * 2);   // NT=14,KT=4

    const int T = 256;

    // ---- MFMA weight packing ----
    k_wpackm<<<cdiv(4 * 2 * 512, T), T, 0, stream>>>(W1, w1b, 54, 54, 2, 4);
    k_wpackm<<<cdiv(7 * 2 * 512, T), T, 0, stream>>>(W2, w2b, 54, 108, 2, 7);
    k_wpackm<<<cdiv(14 * 4 * 512, T), T, 0, stream>>>(W3, w3b, 108, 216, 4, 14);

    // ---- bucketed CSR build ----
    k_zero2<<<cdiv(G * 216, T), T, 0, stream>>>(psum, G * 216, bktCnt, 256);
    k_bkt_hist<<<NBLK_A, 256, 0, stream>>>(col, bktCnt, E, NB);
    k_bkt_scan<<<1, 256, 0, stream>>>(bktCnt, bktOff, bktCur, NB, E);
    k_bkt_part<<<NBLK_A, 256, 0, stream>>>(row, col, bktCur, ebuf, E, NB);
    k_bkt_count<<<NB, 256, 0, stream>>>(ebuf, bktOff, counts, dinv, N);
    k_scan1<<<NCHUNK, 256, 0, stream>>>(counts, rowptr, chunkSums, N);
    k_scan2<<<1, 128, 0, stream>>>(chunkSums, chunkOffs, NCHUNK);
    k_scan3<<<cdiv(N, T), T, 0, stream>>>(rowptr, chunkOffs, N, E);
    k_bkt_fill<<<NB, 256, 0, stream>>>(ebuf, bktOff, rowptr, eSrc, N);
    k_prescale<54><<<cdiv(N * 27, T), T, 0, stream>>>(x, dinv, xs, N);

    // ---- graph boundaries ----
    k_init_start<<<cdiv(G + 1, T), T, 0, stream>>>(start, N, G);
    k_find_start<<<cdiv(N, T), T, 0, stream>>>(batch, start, N);

    const int GB = cdiv(N, 64);  // MFMA gemm blocks (64 nodes each)

    // ---- layer 1: gather(xs) -> MFMA gemm (54 -> 54) ----
    k_gather<54><<<cdiv(N, 4), 256, 0, stream>>>(rowptr, eSrc, dinv, xs, bufA, N);
    k_gemm_mfma<2, 4, 54, 54, false><<<GB, 256, 0, stream>>>(
        bufA, w1b, b1, dinv, nullptr, hsbuf, nullptr, N);

    // ---- layer 2: gather(hs1) -> MFMA gemm (54 -> 108) ----
    k_gather<54><<<cdiv(N, 4), 256, 0, stream>>>(rowptr, eSrc, dinv, hsbuf, bufA, N);
    k_gemm_mfma<2, 7, 54, 108, false><<<GB, 256, 0, stream>>>(
        bufA, w2b, b2, dinv, nullptr, hsbuf, nullptr, N);

    // ---- layer 3: gather(hs2) -> MFMA gemm (108 -> 216) + fused pool ----
    k_gather<108><<<cdiv(N, 4), 256, 0, stream>>>(rowptr, eSrc, dinv, hsbuf, bufA, N);
    k_gemm_mfma<4, 14, 108, 216, true><<<GB, 256, 0, stream>>>(
        bufA, w3b, b3, nullptr, batch, nullptr, psum, N);

    // ---- FC head ----
    k_fc1<<<G * 4, T, 0, stream>>>(psum, start, Wf1, bf1, gbuf);
    k_fc2<<<G, 128, 0, stream>>>(gbuf, Wf2, bf2, out);
}